// Round 1
// baseline (1729.302 us; speedup 1.0000x reference)
//
#include <hip/hip_runtime.h>
#include <hip/hip_bf16.h>

#define N_NODES_C 100000
#define N_EDGES_C 1600000

// ---------------- degree / dinv ----------------
__global__ void count_deg_kernel(const int* __restrict__ dst, float* __restrict__ deg, int n_edges) {
    int e = blockIdx.x * blockDim.x + threadIdx.x;
    if (e < n_edges) atomicAdd(&deg[dst[e]], 1.0f);
}

__global__ void dinv_kernel(float* __restrict__ deg, int n) {
    int i = blockIdx.x * blockDim.x + threadIdx.x;
    if (i < n) deg[i] = rsqrtf(deg[i] + 1.0f);   // +1 self-loop; deg>=1 always
}

// ---------------- self-loop + bias init:  out[i,f] = (bias?b[f]:0) + h[i,f]*dinv[i]^2 ----------------
template <int F, bool BIAS>
__global__ void self_init_kernel(const float* __restrict__ h, const float* __restrict__ dinv,
                                 const float* __restrict__ b, float* __restrict__ out, int n) {
    long long t = (long long)blockIdx.x * blockDim.x + threadIdx.x;
    int node = (int)(t / F);
    int f    = (int)(t % F);
    if (node >= n) return;
    float di = dinv[node];
    float v  = h[t] * di * di;
    if (BIAS) v += b[f];
    out[t] = v;
}

// ---------------- edge scatter-add:  out[dst,f] += h[src,f]*dinv[src]*dinv[dst] ----------------
template <int F, int VEC>
__global__ void edge_agg_kernel(const float* __restrict__ h, const float* __restrict__ dinv,
                                const int* __restrict__ src, const int* __restrict__ dst,
                                float* __restrict__ out, int n_edges) {
    constexpr int TPE = F / VEC;  // threads per edge
    long long t = (long long)blockIdx.x * blockDim.x + threadIdx.x;
    int e = (int)(t / TPE);
    if (e >= n_edges) return;
    int f = (int)(t % TPE) * VEC;
    int s = src[e];
    int d = dst[e];
    float nrm = dinv[s] * dinv[d];
    const float* hr = h + (long long)s * F + f;
    float* orow = out + (long long)d * F + f;
#pragma unroll
    for (int v = 0; v < VEC; ++v) {
        atomicAdd(&orow[v], hr[v] * nrm);
    }
}

// ---------------- small dense GEMM: h[n,OUT] = (relu?)x[n,IN] @ W[IN,OUT] (+b) (relu_out?) ----------------
template <int IN, int OUT, bool RELU_IN, bool RELU_OUT, bool BIAS>
__global__ void gemm_kernel(const float* __restrict__ x, const float* __restrict__ W,
                            const float* __restrict__ b, float* __restrict__ h, int n) {
    __shared__ float sW[IN * OUT];
    __shared__ float sB[OUT];
    for (int i = threadIdx.x; i < IN * OUT; i += blockDim.x) sW[i] = W[i];
    if (BIAS) {
        for (int i = threadIdx.x; i < OUT; i += blockDim.x) sB[i] = b[i];
    }
    __syncthreads();
    long long t = (long long)blockIdx.x * blockDim.x + threadIdx.x;
    int node = (int)(t / OUT);
    int f    = (int)(t % OUT);
    if (node >= n) return;
    const float* xr = x + (long long)node * IN;
    float acc = BIAS ? sB[f] : 0.0f;
#pragma unroll
    for (int k = 0; k < IN; ++k) {
        float v = xr[k];
        if (RELU_IN) v = fmaxf(v, 0.0f);
        acc = fmaf(v, sW[k * OUT + f], acc);
    }
    if (RELU_OUT) acc = fmaxf(acc, 0.0f);
    h[(long long)node * OUT + f] = acc;
}

// ---------------- log_softmax over 2 classes ----------------
__global__ void logsoftmax2_kernel(const float* __restrict__ h, float* __restrict__ out, int n) {
    int i = blockIdx.x * blockDim.x + threadIdx.x;
    if (i >= n) return;
    float a = h[2 * i];
    float b = h[2 * i + 1];
    float m = fmaxf(a, b);
    float lse = m + logf(expf(a - m) + expf(b - m));
    out[2 * i]     = a - lse;
    out[2 * i + 1] = b - lse;
}

static inline int cdiv_ll(long long a, int b) { return (int)((a + b - 1) / b); }

extern "C" void kernel_launch(void* const* d_in, const int* in_sizes, int n_in,
                              void* d_out, int out_size, void* d_ws, size_t ws_size,
                              hipStream_t stream) {
    (void)n_in; (void)out_size; (void)ws_size;

    const float* x  = (const float*)d_in[0];      // [N,18]
    const int*   ei = (const int*)d_in[1];        // [2,E]
    const float* W1 = (const float*)d_in[2];
    const float* b1 = (const float*)d_in[3];
    const float* W2 = (const float*)d_in[4];
    const float* b2 = (const float*)d_in[5];
    const float* W3 = (const float*)d_in[6];
    const float* b3 = (const float*)d_in[7];
    const float* W4 = (const float*)d_in[8];
    const float* b4 = (const float*)d_in[9];

    const int n = in_sizes[0] / 18;               // 100000
    const int E = in_sizes[1] / 2;                // 1600000
    const int* src = ei;
    const int* dst = ei + E;

    // workspace layout (floats)
    float* p = (float*)d_ws;
    float* dinv = p;            p += n;           // deg -> dinv in place
    float* ax   = p;            p += (long long)n * 18;   // aggregated x
    float* h1   = p;            p += (long long)n * 64;   // relu(ax@W1+b1)
    float* h2   = p;            p += (long long)n * 32;   // h1@W2
    float* a2   = p;            p += (long long)n * 32;   // agg(h2)+b2
    float* h3   = p;            p += (long long)n * 16;   // relu(a2)@W3
    float* a3   = p;            p += (long long)n * 16;   // agg(h3)+b3
    float* h4   = p;            p += (long long)n * 2;    // relu(a3)@W4
    float* a4   = p;            p += (long long)n * 2;    // agg(h4)+b4

    const int B = 256;

    // degrees
    hipMemsetAsync(dinv, 0, n * sizeof(float), stream);
    count_deg_kernel<<<cdiv_ll(E, B), B, 0, stream>>>(dst, dinv, E);
    dinv_kernel<<<cdiv_ll(n, B), B, 0, stream>>>(dinv, n);

    // ---- layer 1: aggregate x (18 dims) first, then GEMM 18->64 (+b1, relu) ----
    self_init_kernel<18, false><<<cdiv_ll((long long)n * 18, B), B, 0, stream>>>(x, dinv, nullptr, ax, n);
    edge_agg_kernel<18, 2><<<cdiv_ll((long long)E * 9, B), B, 0, stream>>>(x, dinv, src, dst, ax, E);
    gemm_kernel<18, 64, false, true, true><<<cdiv_ll((long long)n * 64, B), B, 0, stream>>>(ax, W1, b1, h1, n);

    // ---- layer 2: GEMM 64->32, then aggregate (32 dims) + b2; relu fused into next GEMM ----
    gemm_kernel<64, 32, false, false, false><<<cdiv_ll((long long)n * 32, B), B, 0, stream>>>(h1, W2, nullptr, h2, n);
    self_init_kernel<32, true><<<cdiv_ll((long long)n * 32, B), B, 0, stream>>>(h2, dinv, b2, a2, n);
    edge_agg_kernel<32, 4><<<cdiv_ll((long long)E * 8, B), B, 0, stream>>>(h2, dinv, src, dst, a2, E);

    // ---- layer 3: GEMM 32->16 (relu on input), then aggregate + b3 ----
    gemm_kernel<32, 16, true, false, false><<<cdiv_ll((long long)n * 16, B), B, 0, stream>>>(a2, W3, nullptr, h3, n);
    self_init_kernel<16, true><<<cdiv_ll((long long)n * 16, B), B, 0, stream>>>(h3, dinv, b3, a3, n);
    edge_agg_kernel<16, 4><<<cdiv_ll((long long)E * 4, B), B, 0, stream>>>(h3, dinv, src, dst, a3, E);

    // ---- layer 4: GEMM 16->2 (relu on input), then aggregate + b4 ----
    gemm_kernel<16, 2, true, false, false><<<cdiv_ll((long long)n * 2, B), B, 0, stream>>>(a3, W4, nullptr, h4, n);
    self_init_kernel<2, true><<<cdiv_ll((long long)n * 2, B), B, 0, stream>>>(h4, dinv, b4, a4, n);
    edge_agg_kernel<2, 2><<<cdiv_ll((long long)E * 1, B), B, 0, stream>>>(h4, dinv, src, dst, a4, E);

    // ---- log_softmax ----
    logsoftmax2_kernel<<<cdiv_ll(n, B), B, 0, stream>>>(a4, (float*)d_out, n);
}

// Round 2
// 510.349 us; speedup vs baseline: 3.3885x; 3.3885x over previous
//
#include <hip/hip_runtime.h>
#include <hip/hip_bf16.h>

// ============================================================================
// GCN forward, CSR-by-dst counting sort + atomic-free segment aggregation.
//
// Algebra: A_hat(xW) = (A_hat x)W. Layer1 aggregates in 18 dims (pre-GEMM);
// layers 2-4 aggregate post-GEMM (32/16/2 dims). Normalization factored:
//   out[d] = dinv[d] * ( sum_{s in N(d)} h[s]*dinv[s]  +  h[d]*dinv[d] ) + b
// with hs = h * dinv[row] folded into the preceding GEMM epilogue, so the
// aggregation inner loop is a pure gather+add (no atomics, no per-edge norm).
// ============================================================================

#define SCAN_B 256

// ---------------- degree count (int atomics, once per call) ----------------
__global__ void count_deg_kernel(const int* __restrict__ dst, int* __restrict__ deg, int n_edges) {
    int e = blockIdx.x * blockDim.x + threadIdx.x;
    if (e < n_edges) atomicAdd(&deg[dst[e]], 1);
}

__global__ void dinv_kernel(const int* __restrict__ deg, float* __restrict__ dinv, int n) {
    int i = blockIdx.x * blockDim.x + threadIdx.x;
    if (i < n) dinv[i] = rsqrtf((float)deg[i] + 1.0f);   // +1 self-loop
}

// ---------------- exclusive scan (3 kernels) ----------------
__global__ void scan_block_kernel(const int* __restrict__ in, int* __restrict__ out,
                                  int* __restrict__ bsum, int n) {
    __shared__ int s[SCAN_B];
    int i = blockIdx.x * SCAN_B + threadIdx.x;
    int v = (i < n) ? in[i] : 0;
    s[threadIdx.x] = v;
    __syncthreads();
    for (int off = 1; off < SCAN_B; off <<= 1) {
        int t = (threadIdx.x >= off) ? s[threadIdx.x - off] : 0;
        __syncthreads();
        s[threadIdx.x] += t;
        __syncthreads();
    }
    if (i < n) out[i] = s[threadIdx.x] - v;              // exclusive
    if (threadIdx.x == SCAN_B - 1) bsum[blockIdx.x] = s[SCAN_B - 1];
}

__global__ void scan_sums_kernel(int* __restrict__ bsum, int nb) {
    // single block, nb <= 512
    __shared__ int s[512];
    int v = (threadIdx.x < nb) ? bsum[threadIdx.x] : 0;
    s[threadIdx.x] = v;
    __syncthreads();
    for (int off = 1; off < 512; off <<= 1) {
        int t = (threadIdx.x >= off) ? s[threadIdx.x - off] : 0;
        __syncthreads();
        s[threadIdx.x] += t;
        __syncthreads();
    }
    if (threadIdx.x < nb) bsum[threadIdx.x] = s[threadIdx.x] - v;  // exclusive
}

__global__ void scan_add_kernel(int* __restrict__ offsets, int* __restrict__ cursor,
                                const int* __restrict__ bsum, int n, int total) {
    int i = blockIdx.x * SCAN_B + threadIdx.x;
    if (i < n) {
        int v = offsets[i] + bsum[blockIdx.x];
        offsets[i] = v;
        cursor[i]  = v;
    }
    if (i == 0) offsets[n] = total;
}

// ---------------- bucket placement: CSR-by-dst ----------------
__global__ void bucket_kernel(const int* __restrict__ src, const int* __restrict__ dst,
                              int* __restrict__ cursor, int* __restrict__ sorted_src, int n_edges) {
    int e = blockIdx.x * blockDim.x + threadIdx.x;
    if (e >= n_edges) return;
    int d = dst[e];
    int pos = atomicAdd(&cursor[d], 1);
    sorted_src[pos] = src[e];
}

// ---------------- xs = x * dinv[row]  (layer-1 pre-scale, F=18) ----------------
__global__ void scale_rows18_kernel(const float* __restrict__ x, const float* __restrict__ dinv,
                                    float* __restrict__ xs, int n) {
    long long t = (long long)blockIdx.x * blockDim.x + threadIdx.x;
    int node = (int)(t / 18);
    if (node >= n) return;
    xs[t] = x[t] * dinv[node];
}

// ---------------- segment aggregation (atomic-free) ----------------
// out[d, f..f+VEC) = dinv[d]*( sum_{e in seg(d)} hs[s_e] + hs[d] ) (+ b)
template <int F, int VEC, bool BIAS>
__global__ void agg_kernel(const float* __restrict__ hs, const float* __restrict__ dinv,
                           const int* __restrict__ sorted_src, const int* __restrict__ offsets,
                           const float* __restrict__ b, float* __restrict__ out, int n) {
    constexpr int TPE = F / VEC;
    long long t = (long long)blockIdx.x * blockDim.x + threadIdx.x;
    int node = (int)(t / TPE);
    if (node >= n) return;
    int f = (int)(t % TPE) * VEC;
    int beg = offsets[node];
    int end = offsets[node + 1];
    float di = dinv[node];

    float acc[VEC];
    const float* selfr = hs + (long long)node * F + f;
    if constexpr (VEC == 4) {
        float4 v = *reinterpret_cast<const float4*>(selfr);
        acc[0] = v.x; acc[1] = v.y; acc[2] = v.z; acc[3] = v.w;
    } else {
        float2 v = *reinterpret_cast<const float2*>(selfr);
        acc[0] = v.x; acc[1] = v.y;
    }

    for (int e = beg; e < end; ++e) {
        int s = sorted_src[e];
        const float* r = hs + (long long)s * F + f;
        if constexpr (VEC == 4) {
            float4 v = *reinterpret_cast<const float4*>(r);
            acc[0] += v.x; acc[1] += v.y; acc[2] += v.z; acc[3] += v.w;
        } else {
            float2 v = *reinterpret_cast<const float2*>(r);
            acc[0] += v.x; acc[1] += v.y;
        }
    }

    float* o = out + (long long)node * F + f;
#pragma unroll
    for (int v = 0; v < VEC; ++v) {
        float val = acc[v] * di;
        if (BIAS) val += b[f + v];
        o[v] = val;
    }
}

// ---------------- final layer: F=2 aggregation fused with log_softmax ----------------
__global__ void agg2_lsm_kernel(const float* __restrict__ hs, const float* __restrict__ dinv,
                                const int* __restrict__ sorted_src, const int* __restrict__ offsets,
                                const float* __restrict__ b, float* __restrict__ out, int n) {
    int i = blockIdx.x * blockDim.x + threadIdx.x;
    if (i >= n) return;
    int beg = offsets[i];
    int end = offsets[i + 1];
    float di = dinv[i];
    float2 acc = *reinterpret_cast<const float2*>(hs + 2LL * i);
    for (int e = beg; e < end; ++e) {
        int s = sorted_src[e];
        float2 r = *reinterpret_cast<const float2*>(hs + 2LL * s);
        acc.x += r.x; acc.y += r.y;
    }
    float a = acc.x * di + b[0];
    float c = acc.y * di + b[1];
    float m = fmaxf(a, c);
    float lse = m + logf(expf(a - m) + expf(c - m));
    out[2 * i]     = a - lse;
    out[2 * i + 1] = c - lse;
}

// ---------------- small dense GEMM ----------------
// h[node,f] = ((relu_in? relu(x))[node,:] @ W)(+b)(relu_out?)(*dinv[node] if SCALE)
template <int IN, int OUT, bool RELU_IN, bool RELU_OUT, bool BIAS, bool SCALE>
__global__ void gemm_kernel(const float* __restrict__ x, const float* __restrict__ W,
                            const float* __restrict__ b, const float* __restrict__ dinv,
                            float* __restrict__ h, int n) {
    __shared__ float sW[IN * OUT];
    __shared__ float sB[OUT];
    for (int i = threadIdx.x; i < IN * OUT; i += blockDim.x) sW[i] = W[i];
    if (BIAS) {
        for (int i = threadIdx.x; i < OUT; i += blockDim.x) sB[i] = b[i];
    }
    __syncthreads();
    long long t = (long long)blockIdx.x * blockDim.x + threadIdx.x;
    int node = (int)(t / OUT);
    int f    = (int)(t % OUT);
    if (node >= n) return;
    const float* xr = x + (long long)node * IN;
    float acc = BIAS ? sB[f] : 0.0f;
#pragma unroll
    for (int k = 0; k < IN; ++k) {
        float v = xr[k];
        if (RELU_IN) v = fmaxf(v, 0.0f);
        acc = fmaf(v, sW[k * OUT + f], acc);
    }
    if (RELU_OUT) acc = fmaxf(acc, 0.0f);
    if (SCALE) acc *= dinv[node];
    h[(long long)node * OUT + f] = acc;
}

static inline int cdiv_ll(long long a, int b) { return (int)((a + b - 1) / b); }

extern "C" void kernel_launch(void* const* d_in, const int* in_sizes, int n_in,
                              void* d_out, int out_size, void* d_ws, size_t ws_size,
                              hipStream_t stream) {
    (void)n_in; (void)out_size; (void)ws_size;

    const float* x  = (const float*)d_in[0];      // [N,18]
    const int*   ei = (const int*)d_in[1];        // [2,E] (int32 — jax x64 disabled)
    const float* W1 = (const float*)d_in[2];
    const float* b1 = (const float*)d_in[3];
    const float* W2 = (const float*)d_in[4];
    const float* b2 = (const float*)d_in[5];
    const float* W3 = (const float*)d_in[6];
    const float* b3 = (const float*)d_in[7];
    const float* W4 = (const float*)d_in[8];
    const float* b4 = (const float*)d_in[9];

    const int n = in_sizes[0] / 18;               // 100000
    const int E = in_sizes[1] / 2;                // 1600000
    const int* src = ei;
    const int* dst = ei + E;

    const int NB = (n + SCAN_B - 1) / SCAN_B;     // scan blocks (391 <= 512)

    // ---- workspace layout ----
    char* base = (char*)d_ws;
    int*   deg_i      = (int*)base;                 base += (size_t)n * 4;
    int*   offsets    = (int*)base;                 base += (size_t)(n + 1) * 4;
    int*   cursor     = (int*)base;                 base += (size_t)n * 4;
    int*   bsum       = (int*)base;                 base += 512 * 4;
    float* dinv       = (float*)base;               base += (size_t)n * 4;
    int*   sorted_src = (int*)base;                 base += (size_t)E * 4;
    float* xs         = (float*)base;               base += (size_t)n * 18 * 4;  // also h2s (with ax)
    float* ax         = (float*)base;               base += (size_t)n * 18 * 4;
    float* h1         = (float*)base;               base += (size_t)n * 64 * 4;  // also h3s, h4s
    float* a2         = (float*)base;               base += (size_t)n * 32 * 4;
    float* a3         = (float*)base;               base += (size_t)n * 16 * 4;
    // aliases (lifetimes disjoint):
    float* h2s = xs;                      // needs n*32 <= n*36 (xs+ax), live after gemm1
    float* h3s = h1;                      // needs n*16, live after gemm2
    float* h4s = h1 + (size_t)n * 16;     // needs n*2,  live after gemm3

    const int B = 256;

    // ---- CSR-by-dst construction (once per call) ----
    hipMemsetAsync(deg_i, 0, (size_t)n * 4, stream);
    count_deg_kernel<<<cdiv_ll(E, B), B, 0, stream>>>(dst, deg_i, E);
    dinv_kernel<<<cdiv_ll(n, B), B, 0, stream>>>(deg_i, dinv, n);
    scan_block_kernel<<<NB, SCAN_B, 0, stream>>>(deg_i, offsets, bsum, n);
    scan_sums_kernel<<<1, 512, 0, stream>>>(bsum, NB);
    scan_add_kernel<<<NB, SCAN_B, 0, stream>>>(offsets, cursor, bsum, n, E);
    bucket_kernel<<<cdiv_ll(E, B), B, 0, stream>>>(src, dst, cursor, sorted_src, E);

    // ---- layer 1: scale x, aggregate in 18 dims, GEMM 18->64 (+b1, relu) ----
    scale_rows18_kernel<<<cdiv_ll((long long)n * 18, B), B, 0, stream>>>(x, dinv, xs, n);
    agg_kernel<18, 2, false><<<cdiv_ll((long long)n * 9, B), B, 0, stream>>>(
        xs, dinv, sorted_src, offsets, nullptr, ax, n);
    gemm_kernel<18, 64, false, true, true, false><<<cdiv_ll((long long)n * 64, B), B, 0, stream>>>(
        ax, W1, b1, dinv, h1, n);

    // ---- layer 2: GEMM 64->32 (epilogue *dinv), aggregate + b2 ----
    gemm_kernel<64, 32, false, false, false, true><<<cdiv_ll((long long)n * 32, B), B, 0, stream>>>(
        h1, W2, nullptr, dinv, h2s, n);
    agg_kernel<32, 4, true><<<cdiv_ll((long long)n * 8, B), B, 0, stream>>>(
        h2s, dinv, sorted_src, offsets, b2, a2, n);

    // ---- layer 3: GEMM 32->16 (relu_in, *dinv), aggregate + b3 ----
    gemm_kernel<32, 16, true, false, false, true><<<cdiv_ll((long long)n * 16, B), B, 0, stream>>>(
        a2, W3, nullptr, dinv, h3s, n);
    agg_kernel<16, 4, true><<<cdiv_ll((long long)n * 4, B), B, 0, stream>>>(
        h3s, dinv, sorted_src, offsets, b3, a3, n);

    // ---- layer 4: GEMM 16->2 (relu_in, *dinv), aggregate + b4 + log_softmax ----
    gemm_kernel<16, 2, true, false, false, true><<<cdiv_ll((long long)n * 2, B), B, 0, stream>>>(
        a3, W4, nullptr, dinv, h4s, n);
    agg2_lsm_kernel<<<cdiv_ll(n, B), B, 0, stream>>>(
        h4s, dinv, sorted_src, offsets, b4, (float*)d_out, n);
}

// Round 3
// 368.564 us; speedup vs baseline: 4.6920x; 1.3847x over previous
//
#include <hip/hip_runtime.h>
#include <hip/hip_bf16.h>

// ============================================================================
// GCN forward. CSR-by-dst built via two-level bucketed counting sort
// (L2-friendly windows, no global scatter), then atomic-free segment agg.
//
// Algebra: A_hat(xW) = (A_hat x)W. Layer1 aggregates in 18 dims (pre-GEMM);
// layers 2-4 aggregate post-GEMM (32/16/2). Normalization factored:
//   out[d] = dinv[d] * ( sum_{s in N(d)} hs[s] + hs[d] ) + b,  hs = h*dinv[row]
// folded into the preceding GEMM epilogue.
// ============================================================================

#define NBUCK_SHIFT 8            // 256 nodes per bucket
#define PART_CHUNK  4096         // edges per partition block (256 thr x 16)

// ---------------- pass A: bucket histogram ----------------
__global__ __launch_bounds__(256) void hist_kernel(const int* __restrict__ dst,
                                                   int* __restrict__ hist,
                                                   int n_edges, int nbuck) {
    __shared__ int h[512];
    for (int i = threadIdx.x; i < 512; i += 256) h[i] = 0;
    __syncthreads();
    for (long long e = (long long)blockIdx.x * 256 + threadIdx.x; e < n_edges;
         e += (long long)gridDim.x * 256)
        atomicAdd(&h[dst[e] >> NBUCK_SHIFT], 1);
    __syncthreads();
    for (int i = threadIdx.x; i < nbuck; i += 256)
        if (h[i]) atomicAdd(&hist[i], h[i]);
}

// ---------------- pass A': scan bucket sizes (single block) ----------------
__global__ void scan_hist_kernel(const int* __restrict__ hist, int* __restrict__ base,
                                 int* __restrict__ gcur, int nbuck, int total) {
    __shared__ int s[512];
    int v = (threadIdx.x < nbuck) ? hist[threadIdx.x] : 0;
    s[threadIdx.x] = v;
    __syncthreads();
    for (int off = 1; off < 512; off <<= 1) {
        int t = (threadIdx.x >= off) ? s[threadIdx.x - off] : 0;
        __syncthreads();
        s[threadIdx.x] += t;
        __syncthreads();
    }
    if (threadIdx.x < nbuck) {
        int b = s[threadIdx.x] - v;   // exclusive
        base[threadIdx.x] = b;
        gcur[threadIdx.x] = b;
    }
    if (threadIdx.x == 0) base[nbuck] = total;
}

// ---------------- pass B: partition edges into buckets ----------------
__global__ __launch_bounds__(256) void partition_kernel(const int* __restrict__ src,
                                                        const int* __restrict__ dst,
                                                        int* __restrict__ gcur,
                                                        int2* __restrict__ bucketed,
                                                        int n_edges, int nbuck) {
    __shared__ int cnt[512];
    __shared__ int base[512];
    const int t = threadIdx.x;
    for (int i = t; i < 512; i += 256) cnt[i] = 0;
    __syncthreads();
    long long start = (long long)blockIdx.x * PART_CHUNK;
    int sv[16], dv[16], bv[16];
#pragma unroll
    for (int k = 0; k < 16; ++k) {
        long long e = start + (long long)k * 256 + t;
        bool ok = e < n_edges;
        sv[k] = ok ? src[e] : 0;
        dv[k] = ok ? dst[e] : 0;
        bv[k] = ok ? (dv[k] >> NBUCK_SHIFT) : -1;
        if (ok) atomicAdd(&cnt[bv[k]], 1);
    }
    __syncthreads();
    for (int i = t; i < nbuck; i += 256) {
        int c = cnt[i];
        base[i] = c ? atomicAdd(&gcur[i], c) : 0;
    }
    __syncthreads();
    for (int i = t; i < 512; i += 256) cnt[i] = 0;   // reuse as running cursor
    __syncthreads();
#pragma unroll
    for (int k = 0; k < 16; ++k) {
        if (bv[k] >= 0) {
            int pos = base[bv[k]] + atomicAdd(&cnt[bv[k]], 1);
            bucketed[pos] = make_int2(sv[k], dv[k]);
        }
    }
}

// ---------------- pass C: per-bucket CSR finalize (deg, offsets, dinv, place) ----
__global__ __launch_bounds__(256) void csr_kernel(const int2* __restrict__ bucketed,
                                                  const int* __restrict__ base,
                                                  int* __restrict__ offsets,
                                                  float* __restrict__ dinv,
                                                  int* __restrict__ sorted_src,
                                                  int n, int n_edges) {
    __shared__ int ldeg[256];
    __shared__ int lscan[256];
    const int b = blockIdx.x;
    const int t = threadIdx.x;
    const int beg = base[b], end = base[b + 1];
    ldeg[t] = 0;
    __syncthreads();
    for (int e = beg + t; e < end; e += 256) {
        int2 p = bucketed[e];
        atomicAdd(&ldeg[p.y & 255], 1);
    }
    __syncthreads();
    int v = ldeg[t];
    lscan[t] = v;
    __syncthreads();
    for (int off = 1; off < 256; off <<= 1) {
        int x = (t >= off) ? lscan[t - off] : 0;
        __syncthreads();
        lscan[t] += x;
        __syncthreads();
    }
    int excl = lscan[t] - v;                         // exclusive scan
    int node = (b << NBUCK_SHIFT) + t;
    if (node < n) {
        offsets[node] = beg + excl;
        dinv[node]    = rsqrtf((float)v + 1.0f);     // +1 self-loop
    }
    if (b == 0 && t == 0) offsets[n] = n_edges;
    __syncthreads();
    lscan[t] = beg + excl;                           // reuse as placement cursor
    __syncthreads();
    for (int e = beg + t; e < end; e += 256) {
        int2 p = bucketed[e];
        int pos = atomicAdd(&lscan[p.y & 255], 1);
        sorted_src[pos] = p.x;
    }
}

// ---------------- xs = x * dinv[row]  (layer-1 pre-scale, F=18) ----------------
__global__ void scale_rows18_kernel(const float* __restrict__ x, const float* __restrict__ dinv,
                                    float* __restrict__ xs, int n) {
    long long t = (long long)blockIdx.x * blockDim.x + threadIdx.x;
    int node = (int)(t / 18);
    if (node >= n) return;
    xs[t] = x[t] * dinv[node];
}

// ---------------- segment aggregation (atomic-free) ----------------
template <int F, int VEC, bool BIAS>
__global__ void agg_kernel(const float* __restrict__ hs, const float* __restrict__ dinv,
                           const int* __restrict__ sorted_src, const int* __restrict__ offsets,
                           const float* __restrict__ b, float* __restrict__ out, int n) {
    constexpr int TPE = F / VEC;
    long long t = (long long)blockIdx.x * blockDim.x + threadIdx.x;
    int node = (int)(t / TPE);
    if (node >= n) return;
    int f = (int)(t % TPE) * VEC;
    int beg = offsets[node];
    int end = offsets[node + 1];
    float di = dinv[node];

    float acc[VEC];
    const float* selfr = hs + (long long)node * F + f;
    if constexpr (VEC == 4) {
        float4 v = *reinterpret_cast<const float4*>(selfr);
        acc[0] = v.x; acc[1] = v.y; acc[2] = v.z; acc[3] = v.w;
    } else {
        float2 v = *reinterpret_cast<const float2*>(selfr);
        acc[0] = v.x; acc[1] = v.y;
    }

    for (int e = beg; e < end; ++e) {
        int s = sorted_src[e];
        const float* r = hs + (long long)s * F + f;
        if constexpr (VEC == 4) {
            float4 v = *reinterpret_cast<const float4*>(r);
            acc[0] += v.x; acc[1] += v.y; acc[2] += v.z; acc[3] += v.w;
        } else {
            float2 v = *reinterpret_cast<const float2*>(r);
            acc[0] += v.x; acc[1] += v.y;
        }
    }

    float* o = out + (long long)node * F + f;
#pragma unroll
    for (int v = 0; v < VEC; ++v) {
        float val = acc[v] * di;
        if (BIAS) val += b[f + v];
        o[v] = val;
    }
}

// ---------------- final layer: F=2 aggregation fused with log_softmax ----------------
__global__ void agg2_lsm_kernel(const float* __restrict__ hs, const float* __restrict__ dinv,
                                const int* __restrict__ sorted_src, const int* __restrict__ offsets,
                                const float* __restrict__ b, float* __restrict__ out, int n) {
    int i = blockIdx.x * blockDim.x + threadIdx.x;
    if (i >= n) return;
    int beg = offsets[i];
    int end = offsets[i + 1];
    float di = dinv[i];
    float2 acc = *reinterpret_cast<const float2*>(hs + 2LL * i);
    for (int e = beg; e < end; ++e) {
        int s = sorted_src[e];
        float2 r = *reinterpret_cast<const float2*>(hs + 2LL * s);
        acc.x += r.x; acc.y += r.y;
    }
    float a = acc.x * di + b[0];
    float c = acc.y * di + b[1];
    float m = fmaxf(a, c);
    float lse = m + logf(expf(a - m) + expf(c - m));
    out[2 * i]     = a - lse;
    out[2 * i + 1] = c - lse;
}

// ---------------- small dense GEMM ----------------
template <int IN, int OUT, bool RELU_IN, bool RELU_OUT, bool BIAS, bool SCALE>
__global__ void gemm_kernel(const float* __restrict__ x, const float* __restrict__ W,
                            const float* __restrict__ b, const float* __restrict__ dinv,
                            float* __restrict__ h, int n) {
    __shared__ float sW[IN * OUT];
    __shared__ float sB[OUT];
    for (int i = threadIdx.x; i < IN * OUT; i += blockDim.x) sW[i] = W[i];
    if (BIAS) {
        for (int i = threadIdx.x; i < OUT; i += blockDim.x) sB[i] = b[i];
    }
    __syncthreads();
    long long t = (long long)blockIdx.x * blockDim.x + threadIdx.x;
    int node = (int)(t / OUT);
    int f    = (int)(t % OUT);
    if (node >= n) return;
    const float* xr = x + (long long)node * IN;
    float acc = BIAS ? sB[f] : 0.0f;
#pragma unroll
    for (int k = 0; k < IN; ++k) {
        float v = xr[k];
        if (RELU_IN) v = fmaxf(v, 0.0f);
        acc = fmaf(v, sW[k * OUT + f], acc);
    }
    if (RELU_OUT) acc = fmaxf(acc, 0.0f);
    if (SCALE) acc *= dinv[node];
    h[(long long)node * OUT + f] = acc;
}

static inline int cdiv_ll(long long a, int b) { return (int)((a + b - 1) / b); }

extern "C" void kernel_launch(void* const* d_in, const int* in_sizes, int n_in,
                              void* d_out, int out_size, void* d_ws, size_t ws_size,
                              hipStream_t stream) {
    (void)n_in; (void)out_size; (void)ws_size;

    const float* x  = (const float*)d_in[0];      // [N,18]
    const int*   ei = (const int*)d_in[1];        // [2,E]
    const float* W1 = (const float*)d_in[2];
    const float* b1 = (const float*)d_in[3];
    const float* W2 = (const float*)d_in[4];
    const float* b2 = (const float*)d_in[5];
    const float* W3 = (const float*)d_in[6];
    const float* b3 = (const float*)d_in[7];
    const float* W4 = (const float*)d_in[8];
    const float* b4 = (const float*)d_in[9];

    const int n = in_sizes[0] / 18;               // 100000
    const int E = in_sizes[1] / 2;                // 1600000
    const int* src = ei;
    const int* dst = ei + E;
    const int nbuck = (n + 255) >> NBUCK_SHIFT;   // 391

    // ---- workspace layout ----
    char* base = (char*)d_ws;
    int*   hist       = (int*)base;                 base += 512 * 4;
    int*   bbase      = (int*)base;                 base += 512 * 4;   // bucket offsets (+1)
    int*   gcur       = (int*)base;                 base += 512 * 4;
    int*   offsets    = (int*)base;                 base += (size_t)(n + 1) * 4;
    float* dinv       = (float*)base;               base += (size_t)n * 4;
    int*   sorted_src = (int*)base;                 base += (size_t)E * 4;
    float* xs         = (float*)base;               base += (size_t)n * 18 * 4;
    float* ax         = (float*)base;               base += (size_t)n * 18 * 4;
    float* h1         = (float*)base;               base += (size_t)n * 64 * 4;
    float* a2         = (float*)base;               base += (size_t)n * 32 * 4;
    float* a3         = (float*)base;               base += (size_t)n * 16 * 4;
    // aliases (lifetimes disjoint):
    int2*  bucketed = (int2*)h1;          // E*8B = 12.8MB <= n*64*4 = 25.6MB; dead before gemm1
    float* h2s = xs;                      // n*32 <= n*36 (xs+ax), live after gemm1
    float* h3s = h1;                      // n*16, live after gemm2
    float* h4s = h1 + (size_t)n * 16;     // n*2,  live after gemm3

    const int B = 256;

    // ---- CSR-by-dst via bucketed counting sort ----
    hipMemsetAsync(hist, 0, 512 * 4, stream);
    hist_kernel<<<512, B, 0, stream>>>(dst, hist, E, nbuck);
    scan_hist_kernel<<<1, 512, 0, stream>>>(hist, bbase, gcur, nbuck, E);
    partition_kernel<<<cdiv_ll(E, PART_CHUNK), B, 0, stream>>>(src, dst, gcur, bucketed, E, nbuck);
    csr_kernel<<<nbuck, B, 0, stream>>>(bucketed, bbase, offsets, dinv, sorted_src, n, E);

    // ---- layer 1: scale x, aggregate in 18 dims, GEMM 18->64 (+b1, relu) ----
    scale_rows18_kernel<<<cdiv_ll((long long)n * 18, B), B, 0, stream>>>(x, dinv, xs, n);
    agg_kernel<18, 2, false><<<cdiv_ll((long long)n * 9, B), B, 0, stream>>>(
        xs, dinv, sorted_src, offsets, nullptr, ax, n);
    gemm_kernel<18, 64, false, true, true, false><<<cdiv_ll((long long)n * 64, B), B, 0, stream>>>(
        ax, W1, b1, dinv, h1, n);

    // ---- layer 2: GEMM 64->32 (epilogue *dinv), aggregate + b2 ----
    gemm_kernel<64, 32, false, false, false, true><<<cdiv_ll((long long)n * 32, B), B, 0, stream>>>(
        h1, W2, nullptr, dinv, h2s, n);
    agg_kernel<32, 4, true><<<cdiv_ll((long long)n * 8, B), B, 0, stream>>>(
        h2s, dinv, sorted_src, offsets, b2, a2, n);

    // ---- layer 3: GEMM 32->16 (relu_in, *dinv), aggregate + b3 ----
    gemm_kernel<32, 16, true, false, false, true><<<cdiv_ll((long long)n * 16, B), B, 0, stream>>>(
        a2, W3, nullptr, dinv, h3s, n);
    agg_kernel<16, 4, true><<<cdiv_ll((long long)n * 4, B), B, 0, stream>>>(
        h3s, dinv, sorted_src, offsets, b3, a3, n);

    // ---- layer 4: GEMM 16->2 (relu_in, *dinv), aggregate + b4 + log_softmax ----
    gemm_kernel<16, 2, true, false, false, true><<<cdiv_ll((long long)n * 2, B), B, 0, stream>>>(
        a3, W4, nullptr, dinv, h4s, n);
    agg2_lsm_kernel<<<cdiv_ll(n, B), B, 0, stream>>>(
        h4s, dinv, sorted_src, offsets, b4, (float*)d_out, n);
}

// Round 4
// 327.494 us; speedup vs baseline: 5.2804x; 1.1254x over previous
//
#include <hip/hip_runtime.h>
#include <hip/hip_bf16.h>
#include <hip/hip_fp16.h>

// ============================================================================
// GCN forward. CSR-by-dst via two-level bucketed counting sort, atomic-free
// segment aggregation with fp16 gather tables (fp32 accumulation).
//
// Algebra: A_hat(xW) = (A_hat x)W. Layer1 aggregates in 18 dims (pre-GEMM);
// layers 2-4 aggregate post-GEMM (32/16/2). Normalization factored:
//   out[d] = dinv[d] * ( sum_{s in N(d)} hs[s] + hs[d] ) + b,  hs = h*dinv[row]
// folded into the preceding GEMM epilogue. Gather tables stored fp16 so they
// (mostly) fit the 4 MiB per-XCD L2: 18d=3.6MB, 32d=6.4MB, 16d=3.2MB.
// ============================================================================

#define NBUCK_SHIFT 8            // 256 nodes per bucket
#define PART_CHUNK  4096         // edges per partition block (256 thr x 16)

// ---------------- pass A: bucket histogram ----------------
__global__ __launch_bounds__(256) void hist_kernel(const int* __restrict__ dst,
                                                   int* __restrict__ hist,
                                                   int n_edges, int nbuck) {
    __shared__ int h[512];
    for (int i = threadIdx.x; i < 512; i += 256) h[i] = 0;
    __syncthreads();
    for (long long e = (long long)blockIdx.x * 256 + threadIdx.x; e < n_edges;
         e += (long long)gridDim.x * 256)
        atomicAdd(&h[dst[e] >> NBUCK_SHIFT], 1);
    __syncthreads();
    for (int i = threadIdx.x; i < nbuck; i += 256)
        if (h[i]) atomicAdd(&hist[i], h[i]);
}

// ---------------- pass A': scan bucket sizes (single block) ----------------
__global__ void scan_hist_kernel(const int* __restrict__ hist, int* __restrict__ base,
                                 int* __restrict__ gcur, int nbuck, int total) {
    __shared__ int s[512];
    int v = (threadIdx.x < nbuck) ? hist[threadIdx.x] : 0;
    s[threadIdx.x] = v;
    __syncthreads();
    for (int off = 1; off < 512; off <<= 1) {
        int t = (threadIdx.x >= off) ? s[threadIdx.x - off] : 0;
        __syncthreads();
        s[threadIdx.x] += t;
        __syncthreads();
    }
    if (threadIdx.x < nbuck) {
        int b = s[threadIdx.x] - v;   // exclusive
        base[threadIdx.x] = b;
        gcur[threadIdx.x] = b;
    }
    if (threadIdx.x == 0) base[nbuck] = total;
}

// ---------------- pass B: partition edges into buckets ----------------
// staged word: (src << 8) | (dst & 255)   [src < 2^24, bucket-local dst is 8b]
__global__ __launch_bounds__(256) void partition_kernel(const int* __restrict__ src,
                                                        const int* __restrict__ dst,
                                                        int* __restrict__ gcur,
                                                        unsigned int* __restrict__ bucketed,
                                                        int n_edges, int nbuck) {
    __shared__ int cnt[512];
    __shared__ int base[512];
    const int t = threadIdx.x;
    for (int i = t; i < 512; i += 256) cnt[i] = 0;
    __syncthreads();
    long long start = (long long)blockIdx.x * PART_CHUNK;
    int sv[16], dv[16], bv[16];
#pragma unroll
    for (int k = 0; k < 16; ++k) {
        long long e = start + (long long)k * 256 + t;
        bool ok = e < n_edges;
        sv[k] = ok ? src[e] : 0;
        dv[k] = ok ? dst[e] : 0;
        bv[k] = ok ? (dv[k] >> NBUCK_SHIFT) : -1;
        if (ok) atomicAdd(&cnt[bv[k]], 1);
    }
    __syncthreads();
    for (int i = t; i < nbuck; i += 256) {
        int c = cnt[i];
        base[i] = c ? atomicAdd(&gcur[i], c) : 0;
    }
    __syncthreads();
    for (int i = t; i < 512; i += 256) cnt[i] = 0;   // reuse as running cursor
    __syncthreads();
#pragma unroll
    for (int k = 0; k < 16; ++k) {
        if (bv[k] >= 0) {
            int pos = base[bv[k]] + atomicAdd(&cnt[bv[k]], 1);
            bucketed[pos] = ((unsigned int)sv[k] << 8) | (unsigned int)(dv[k] & 255);
        }
    }
}

// ---------------- pass C: per-bucket CSR finalize ----------------
__global__ __launch_bounds__(256) void csr_kernel(const unsigned int* __restrict__ bucketed,
                                                  const int* __restrict__ base,
                                                  int* __restrict__ offsets,
                                                  float* __restrict__ dinv,
                                                  int* __restrict__ sorted_src,
                                                  int n, int n_edges) {
    __shared__ int ldeg[256];
    __shared__ int lscan[256];
    const int b = blockIdx.x;
    const int t = threadIdx.x;
    const int beg = base[b], end = base[b + 1];
    ldeg[t] = 0;
    __syncthreads();
    for (int e = beg + t; e < end; e += 256) {
        unsigned int p = bucketed[e];
        atomicAdd(&ldeg[p & 255u], 1);
    }
    __syncthreads();
    int v = ldeg[t];
    lscan[t] = v;
    __syncthreads();
    for (int off = 1; off < 256; off <<= 1) {
        int x = (t >= off) ? lscan[t - off] : 0;
        __syncthreads();
        lscan[t] += x;
        __syncthreads();
    }
    int excl = lscan[t] - v;                         // exclusive scan
    int node = (b << NBUCK_SHIFT) + t;
    if (node < n) {
        offsets[node] = beg + excl;
        dinv[node]    = rsqrtf((float)v + 1.0f);     // +1 self-loop
    }
    if (b == 0 && t == 0) offsets[n] = n_edges;
    __syncthreads();
    lscan[t] = beg + excl;                           // reuse as placement cursor
    __syncthreads();
    for (int e = beg + t; e < end; e += 256) {
        unsigned int p = bucketed[e];
        int pos = atomicAdd(&lscan[p & 255u], 1);
        sorted_src[pos] = (int)(p >> 8);
    }
}

// ---------------- xs = half(x * dinv[row])  (layer-1 pre-scale, F=18) --------
__global__ void scale_rows18_kernel(const float* __restrict__ x, const float* __restrict__ dinv,
                                    __half* __restrict__ xs, int n) {
    long long t = (long long)blockIdx.x * blockDim.x + threadIdx.x;
    int node = (int)(t / 18);
    if (node >= n) return;
    xs[t] = __float2half(x[t] * dinv[node]);
}

// ---------------- segment aggregation from fp16 table (fp32 accumulate) -----
// VECH halves per thread; TPE = F/VECH threads per node.
template <int F, int VECH, bool BIAS>
__global__ void agg_h_kernel(const __half* __restrict__ hs, const float* __restrict__ dinv,
                             const int* __restrict__ sorted_src, const int* __restrict__ offsets,
                             const float* __restrict__ b, float* __restrict__ out, int n) {
    constexpr int TPE = F / VECH;
    long long t = (long long)blockIdx.x * blockDim.x + threadIdx.x;
    int node = (int)(t / TPE);
    if (node >= n) return;
    int f = (int)(t % TPE) * VECH;
    int beg = offsets[node];
    int end = offsets[node + 1];
    float di = dinv[node];

    float acc[VECH];
    {
        const __half* selfr = hs + (long long)node * F + f;
        if constexpr (VECH == 8) {
            float4 raw = *reinterpret_cast<const float4*>(selfr);
            const __half2* h2 = reinterpret_cast<const __half2*>(&raw);
#pragma unroll
            for (int j = 0; j < 4; ++j) {
                float2 v = __half22float2(h2[j]);
                acc[2 * j] = v.x; acc[2 * j + 1] = v.y;
            }
        } else {
            float2 v = __half22float2(*reinterpret_cast<const __half2*>(selfr));
            acc[0] = v.x; acc[1] = v.y;
        }
    }

    for (int e = beg; e < end; ++e) {
        int s = sorted_src[e];
        const __half* r = hs + (long long)s * F + f;
        if constexpr (VECH == 8) {
            float4 raw = *reinterpret_cast<const float4*>(r);
            const __half2* h2 = reinterpret_cast<const __half2*>(&raw);
#pragma unroll
            for (int j = 0; j < 4; ++j) {
                float2 v = __half22float2(h2[j]);
                acc[2 * j] += v.x; acc[2 * j + 1] += v.y;
            }
        } else {
            float2 v = __half22float2(*reinterpret_cast<const __half2*>(r));
            acc[0] += v.x; acc[1] += v.y;
        }
    }

    float* o = out + (long long)node * F + f;
#pragma unroll
    for (int v = 0; v < VECH; ++v) {
        float val = acc[v] * di;
        if (BIAS) val += b[f + v];
        o[v] = val;
    }
}

// ---------------- final layer: F=2 fp16 aggregation fused with log_softmax ---
__global__ void agg2_lsm_kernel(const __half* __restrict__ hs, const float* __restrict__ dinv,
                                const int* __restrict__ sorted_src, const int* __restrict__ offsets,
                                const float* __restrict__ b, float* __restrict__ out, int n) {
    int i = blockIdx.x * blockDim.x + threadIdx.x;
    if (i >= n) return;
    int beg = offsets[i];
    int end = offsets[i + 1];
    float di = dinv[i];
    float2 acc = __half22float2(*reinterpret_cast<const __half2*>(hs + 2LL * i));
    for (int e = beg; e < end; ++e) {
        int s = sorted_src[e];
        float2 r = __half22float2(*reinterpret_cast<const __half2*>(hs + 2LL * s));
        acc.x += r.x; acc.y += r.y;
    }
    float a = acc.x * di + b[0];
    float c = acc.y * di + b[1];
    float m = fmaxf(a, c);
    float lse = m + logf(expf(a - m) + expf(c - m));
    out[2 * i]     = a - lse;
    out[2 * i + 1] = c - lse;
}

// ---------------- small dense GEMM (float in, float or half out) -------------
__device__ inline void store_val(float* p, float v)  { *p = v; }
__device__ inline void store_val(__half* p, float v) { *p = __float2half(v); }

template <int IN, int OUT, bool RELU_IN, bool RELU_OUT, bool BIAS, bool SCALE, typename OutT>
__global__ void gemm_kernel(const float* __restrict__ x, const float* __restrict__ W,
                            const float* __restrict__ b, const float* __restrict__ dinv,
                            OutT* __restrict__ h, int n) {
    __shared__ float sW[IN * OUT];
    __shared__ float sB[OUT];
    for (int i = threadIdx.x; i < IN * OUT; i += blockDim.x) sW[i] = W[i];
    if (BIAS) {
        for (int i = threadIdx.x; i < OUT; i += blockDim.x) sB[i] = b[i];
    }
    __syncthreads();
    long long t = (long long)blockIdx.x * blockDim.x + threadIdx.x;
    int node = (int)(t / OUT);
    int f    = (int)(t % OUT);
    if (node >= n) return;
    const float* xr = x + (long long)node * IN;
    float acc = BIAS ? sB[f] : 0.0f;
#pragma unroll
    for (int k = 0; k < IN; ++k) {
        float v = xr[k];
        if (RELU_IN) v = fmaxf(v, 0.0f);
        acc = fmaf(v, sW[k * OUT + f], acc);
    }
    if (RELU_OUT) acc = fmaxf(acc, 0.0f);
    if (SCALE) acc *= dinv[node];
    store_val(&h[(long long)node * OUT + f], acc);
}

static inline int cdiv_ll(long long a, int b) { return (int)((a + b - 1) / b); }
static inline char* align16(char* p) { return (char*)(((uintptr_t)p + 15) & ~(uintptr_t)15); }

extern "C" void kernel_launch(void* const* d_in, const int* in_sizes, int n_in,
                              void* d_out, int out_size, void* d_ws, size_t ws_size,
                              hipStream_t stream) {
    (void)n_in; (void)out_size; (void)ws_size;

    const float* x  = (const float*)d_in[0];      // [N,18]
    const int*   ei = (const int*)d_in[1];        // [2,E]
    const float* W1 = (const float*)d_in[2];
    const float* b1 = (const float*)d_in[3];
    const float* W2 = (const float*)d_in[4];
    const float* b2 = (const float*)d_in[5];
    const float* W3 = (const float*)d_in[6];
    const float* b3 = (const float*)d_in[7];
    const float* W4 = (const float*)d_in[8];
    const float* b4 = (const float*)d_in[9];

    const int n = in_sizes[0] / 18;               // 100000
    const int E = in_sizes[1] / 2;                // 1600000
    const int* src = ei;
    const int* dst = ei + E;
    const int nbuck = (n + 255) >> NBUCK_SHIFT;   // 391

    // ---- workspace layout (16B-aligned regions) ----
    char* p = (char*)d_ws;
    int*   hist       = (int*)p;               p = align16(p + 512 * 4);
    int*   bbase      = (int*)p;               p = align16(p + 512 * 4);
    int*   gcur       = (int*)p;               p = align16(p + 512 * 4);
    int*   offsets    = (int*)p;               p = align16(p + (size_t)(n + 1) * 4);
    float* dinv       = (float*)p;             p = align16(p + (size_t)n * 4);
    int*   sorted_src = (int*)p;               p = align16(p + (size_t)E * 4);
    __half* xs        = (__half*)p;            p = align16(p + (size_t)n * 18 * 2);  // 3.6MB
    float* ax         = (float*)p;             p = align16(p + (size_t)n * 18 * 4);  // 7.2MB
    float* h1         = (float*)p;             p = align16(p + (size_t)n * 64 * 4);  // 25.6MB
    float* a2         = (float*)p;             p = align16(p + (size_t)n * 32 * 4);  // 12.8MB
    float* a3         = (float*)p;             p = align16(p + (size_t)n * 16 * 4);  // 6.4MB
    // aliases (lifetimes disjoint):
    unsigned int* bucketed = (unsigned int*)h1;   // E*4 = 6.4MB <= 25.6MB; dead before gemm1
    __half* h2s = (__half*)xs;            // n*32*2 = 6.4MB <= xs+ax (10.8MB); live after gemm1
    __half* h3s = (__half*)h1;            // n*16*2 = 3.2MB; live after gemm2
    __half* h4s = (__half*)(h1 + (size_t)n * 16); // n*2*2 = 0.4MB; live after gemm3

    const int B = 256;

    // ---- CSR-by-dst via bucketed counting sort ----
    hipMemsetAsync(hist, 0, 512 * 4, stream);
    hist_kernel<<<512, B, 0, stream>>>(dst, hist, E, nbuck);
    scan_hist_kernel<<<1, 512, 0, stream>>>(hist, bbase, gcur, nbuck, E);
    partition_kernel<<<cdiv_ll(E, PART_CHUNK), B, 0, stream>>>(src, dst, gcur, bucketed, E, nbuck);
    csr_kernel<<<nbuck, B, 0, stream>>>(bucketed, bbase, offsets, dinv, sorted_src, n, E);

    // ---- layer 1: scale x -> fp16, aggregate 18 dims, GEMM 18->64 (+b1, relu) ----
    scale_rows18_kernel<<<cdiv_ll((long long)n * 18, B), B, 0, stream>>>(x, dinv, xs, n);
    agg_h_kernel<18, 2, false><<<cdiv_ll((long long)n * 9, B), B, 0, stream>>>(
        xs, dinv, sorted_src, offsets, nullptr, ax, n);
    gemm_kernel<18, 64, false, true, true, false><<<cdiv_ll((long long)n * 64, B), B, 0, stream>>>(
        ax, W1, b1, dinv, h1, n);

    // ---- layer 2: GEMM 64->32 (epilogue *dinv -> fp16), aggregate + b2 ----
    gemm_kernel<64, 32, false, false, false, true><<<cdiv_ll((long long)n * 32, B), B, 0, stream>>>(
        h1, W2, nullptr, dinv, h2s, n);
    agg_h_kernel<32, 8, true><<<cdiv_ll((long long)n * 4, B), B, 0, stream>>>(
        h2s, dinv, sorted_src, offsets, b2, a2, n);

    // ---- layer 3: GEMM 32->16 (relu_in, *dinv -> fp16), aggregate + b3 ----
    gemm_kernel<32, 16, true, false, false, true><<<cdiv_ll((long long)n * 16, B), B, 0, stream>>>(
        a2, W3, nullptr, dinv, h3s, n);
    agg_h_kernel<16, 8, true><<<cdiv_ll((long long)n * 2, B), B, 0, stream>>>(
        h3s, dinv, sorted_src, offsets, b3, a3, n);

    // ---- layer 4: GEMM 16->2 (relu_in, *dinv -> fp16), aggregate + b4 + lsm ----
    gemm_kernel<16, 2, true, false, false, true><<<cdiv_ll((long long)n * 2, B), B, 0, stream>>>(
        a3, W4, nullptr, dinv, h4s, n);
    agg2_lsm_kernel<<<cdiv_ll(n, B), B, 0, stream>>>(
        h4s, dinv, sorted_src, offsets, b4, (float*)d_out, n);
}

// Round 5
// 266.742 us; speedup vs baseline: 6.4831x; 1.2278x over previous
//
#include <hip/hip_runtime.h>
#include <hip/hip_bf16.h>
#include <hip/hip_fp16.h>

// ============================================================================
// GCN forward. CSR-by-dst via two-level bucketed counting sort; then three
// fused "gather + dense" layer kernels (TPE=1: one thread owns a node row,
// edge list read once per layer, aggregated row stays in registers and the
// following dense layer(s) are applied in-thread with LDS-resident weights).
//
// Algebra: A_hat(xW) = (A_hat x)W, normalization factored as
//   out[d] = dinv[d] * ( sum_{s in N(d)} hs[s] + hs[d] ) + b,  hs = h*dinv[row]
// with hs stored fp16 (fp32 accumulation). Tables: xs=4.8MB, h2s=6.4MB,
// h3s=3.2MB, h4s=0.4MB -> L2/L3 resident gathers.
// ============================================================================

#define NBUCK_SHIFT 8            // 256 nodes per bucket
#define PART_CHUNK  4096         // edges per partition block (256 thr x 16)

// ---------------- pass A: bucket histogram ----------------
__global__ __launch_bounds__(256) void hist_kernel(const int* __restrict__ dst,
                                                   int* __restrict__ hist,
                                                   int n_edges, int nbuck) {
    __shared__ int h[512];
    for (int i = threadIdx.x; i < 512; i += 256) h[i] = 0;
    __syncthreads();
    for (long long e = (long long)blockIdx.x * 256 + threadIdx.x; e < n_edges;
         e += (long long)gridDim.x * 256)
        atomicAdd(&h[dst[e] >> NBUCK_SHIFT], 1);
    __syncthreads();
    for (int i = threadIdx.x; i < nbuck; i += 256)
        if (h[i]) atomicAdd(&hist[i], h[i]);
}

// ---------------- pass A': scan bucket sizes (single block) ----------------
__global__ void scan_hist_kernel(const int* __restrict__ hist, int* __restrict__ base,
                                 int* __restrict__ gcur, int nbuck, int total) {
    __shared__ int s[512];
    int v = (threadIdx.x < nbuck) ? hist[threadIdx.x] : 0;
    s[threadIdx.x] = v;
    __syncthreads();
    for (int off = 1; off < 512; off <<= 1) {
        int t = (threadIdx.x >= off) ? s[threadIdx.x - off] : 0;
        __syncthreads();
        s[threadIdx.x] += t;
        __syncthreads();
    }
    if (threadIdx.x < nbuck) {
        int b = s[threadIdx.x] - v;   // exclusive
        base[threadIdx.x] = b;
        gcur[threadIdx.x] = b;
    }
    if (threadIdx.x == 0) base[nbuck] = total;
}

// ---------------- pass B: partition edges into buckets ----------------
// staged word: (src << 8) | (dst & 255)
__global__ __launch_bounds__(256) void partition_kernel(const int* __restrict__ src,
                                                        const int* __restrict__ dst,
                                                        int* __restrict__ gcur,
                                                        unsigned int* __restrict__ bucketed,
                                                        int n_edges, int nbuck) {
    __shared__ int cnt[512];
    __shared__ int base[512];
    const int t = threadIdx.x;
    for (int i = t; i < 512; i += 256) cnt[i] = 0;
    __syncthreads();
    long long start = (long long)blockIdx.x * PART_CHUNK;
    int sv[16], dv[16], bv[16];
#pragma unroll
    for (int k = 0; k < 16; ++k) {
        long long e = start + (long long)k * 256 + t;
        bool ok = e < n_edges;
        sv[k] = ok ? src[e] : 0;
        dv[k] = ok ? dst[e] : 0;
        bv[k] = ok ? (dv[k] >> NBUCK_SHIFT) : -1;
        if (ok) atomicAdd(&cnt[bv[k]], 1);
    }
    __syncthreads();
    for (int i = t; i < nbuck; i += 256) {
        int c = cnt[i];
        base[i] = c ? atomicAdd(&gcur[i], c) : 0;
    }
    __syncthreads();
    for (int i = t; i < 512; i += 256) cnt[i] = 0;   // reuse as running cursor
    __syncthreads();
#pragma unroll
    for (int k = 0; k < 16; ++k) {
        if (bv[k] >= 0) {
            int pos = base[bv[k]] + atomicAdd(&cnt[bv[k]], 1);
            bucketed[pos] = ((unsigned int)sv[k] << 8) | (unsigned int)(dv[k] & 255);
        }
    }
}

// ---------------- pass C: per-bucket CSR finalize ----------------
__global__ __launch_bounds__(256) void csr_kernel(const unsigned int* __restrict__ bucketed,
                                                  const int* __restrict__ base,
                                                  int* __restrict__ offsets,
                                                  float* __restrict__ dinv,
                                                  int* __restrict__ sorted_src,
                                                  int n, int n_edges) {
    __shared__ int ldeg[256];
    __shared__ int lscan[256];
    const int b = blockIdx.x;
    const int t = threadIdx.x;
    const int beg = base[b], end = base[b + 1];
    ldeg[t] = 0;
    __syncthreads();
    for (int e = beg + t; e < end; e += 256) {
        unsigned int p = bucketed[e];
        atomicAdd(&ldeg[p & 255u], 1);
    }
    __syncthreads();
    int v = ldeg[t];
    lscan[t] = v;
    __syncthreads();
    for (int off = 1; off < 256; off <<= 1) {
        int x = (t >= off) ? lscan[t - off] : 0;
        __syncthreads();
        lscan[t] += x;
        __syncthreads();
    }
    int excl = lscan[t] - v;                         // exclusive scan
    int node = (b << NBUCK_SHIFT) + t;
    if (node < n) {
        offsets[node] = beg + excl;
        dinv[node]    = rsqrtf((float)v + 1.0f);     // +1 self-loop
    }
    if (b == 0 && t == 0) offsets[n] = n_edges;
    __syncthreads();
    lscan[t] = beg + excl;                           // reuse as placement cursor
    __syncthreads();
    for (int e = beg + t; e < end; e += 256) {
        unsigned int p = bucketed[e];
        int pos = atomicAdd(&lscan[p & 255u], 1);
        sorted_src[pos] = (int)(p >> 8);
    }
}

// ---------------- helpers ----------------
__device__ inline void acc8(float* acc, float4 raw) {
    const __half2* h2 = reinterpret_cast<const __half2*>(&raw);
#pragma unroll
    for (int j = 0; j < 4; ++j) {
        float2 v = __half22float2(h2[j]);
        acc[2 * j]     += v.x;
        acc[2 * j + 1] += v.y;
    }
}
__device__ inline void set8(float* acc, float4 raw) {
    const __half2* h2 = reinterpret_cast<const __half2*>(&raw);
#pragma unroll
    for (int j = 0; j < 4; ++j) {
        float2 v = __half22float2(h2[j]);
        acc[2 * j]     = v.x;
        acc[2 * j + 1] = v.y;
    }
}
__device__ inline float4 pack8(const float* v) {
    float4 out;
    __half2* h2 = reinterpret_cast<__half2*>(&out);
#pragma unroll
    for (int j = 0; j < 4; ++j) h2[j] = __floats2half2_rn(v[2 * j], v[2 * j + 1]);
    return out;
}

// ---------------- xs[node, 0..23] = half(x[node,0..17] * dinv[node]), padded --
__global__ __launch_bounds__(256) void scale_pad18_kernel(const float* __restrict__ x,
                                                          const float* __restrict__ dinv,
                                                          __half* __restrict__ xs, int n) {
    int node = blockIdx.x * 256 + threadIdx.x;
    if (node >= n) return;
    float di = dinv[node];
    const float* xr = x + (long long)node * 18;
    float v[24];
#pragma unroll
    for (int k = 0; k < 18; ++k) v[k] = xr[k] * di;
#pragma unroll
    for (int k = 18; k < 24; ++k) v[k] = 0.0f;
    float4* o = reinterpret_cast<float4*>(xs + (long long)node * 24);
    o[0] = pack8(v);
    o[1] = pack8(v + 8);
    o[2] = pack8(v + 16);
}

// ---------------- fused layer 1+2: gather(18) -> 18->64 relu -> 64->32 *di ---
__global__ __launch_bounds__(256) void layer12_kernel(
    const __half* __restrict__ xs, const float* __restrict__ dinv,
    const int* __restrict__ sorted_src, const int* __restrict__ offsets,
    const float* __restrict__ W1, const float* __restrict__ b1,
    const float* __restrict__ W2, __half* __restrict__ h2s, int n) {
    __shared__ float sW1[18 * 64];
    __shared__ float sB1[64];
    __shared__ float sW2[64 * 32];
    for (int i = threadIdx.x; i < 18 * 64; i += 256) sW1[i] = W1[i];
    for (int i = threadIdx.x; i < 64; i += 256) sB1[i] = b1[i];
    for (int i = threadIdx.x; i < 64 * 32; i += 256) sW2[i] = W2[i];
    __syncthreads();
    int node = blockIdx.x * 256 + threadIdx.x;
    if (node >= n) return;
    int beg = offsets[node], end = offsets[node + 1];
    float di = dinv[node];

    float acc[24];
    {
        const float4* p = reinterpret_cast<const float4*>(xs + (long long)node * 24);
        set8(acc, p[0]); set8(acc + 8, p[1]); set8(acc + 16, p[2]);
    }
    for (int e = beg; e < end; ++e) {
        int s = sorted_src[e];
        const float4* p = reinterpret_cast<const float4*>(xs + (long long)s * 24);
        acc8(acc, p[0]); acc8(acc + 8, p[1]); acc8(acc + 16, p[2]);
    }

    // hidden = relu( (acc*di) @ W1 + b1 )
    float hidden[64];
#pragma unroll
    for (int j = 0; j < 64; ++j) hidden[j] = sB1[j];
#pragma unroll
    for (int k = 0; k < 18; ++k) {
        float a = acc[k] * di;
#pragma unroll
        for (int j = 0; j < 64; ++j) hidden[j] = fmaf(a, sW1[k * 64 + j], hidden[j]);
    }
#pragma unroll
    for (int j = 0; j < 64; ++j) hidden[j] = fmaxf(hidden[j], 0.0f);

    // out = (hidden @ W2) * di  -> fp16
    float out[32];
#pragma unroll
    for (int f = 0; f < 32; ++f) out[f] = 0.0f;
#pragma unroll
    for (int j = 0; j < 64; ++j) {
        float a = hidden[j];
#pragma unroll
        for (int f = 0; f < 32; ++f) out[f] = fmaf(a, sW2[j * 32 + f], out[f]);
    }
#pragma unroll
    for (int f = 0; f < 32; ++f) out[f] *= di;

    float4* o = reinterpret_cast<float4*>(h2s + (long long)node * 32);
    o[0] = pack8(out);
    o[1] = pack8(out + 8);
    o[2] = pack8(out + 16);
    o[3] = pack8(out + 24);
}

// ---------------- fused layer 3: gather(32) -> +b2 relu -> 32->16 *di --------
__global__ __launch_bounds__(256) void layer3_kernel(
    const __half* __restrict__ h2s, const float* __restrict__ dinv,
    const int* __restrict__ sorted_src, const int* __restrict__ offsets,
    const float* __restrict__ b2, const float* __restrict__ W3,
    __half* __restrict__ h3s, int n) {
    __shared__ float sW3[32 * 16];
    __shared__ float sB2[32];
    for (int i = threadIdx.x; i < 32 * 16; i += 256) sW3[i] = W3[i];
    for (int i = threadIdx.x; i < 32; i += 256) sB2[i] = b2[i];
    __syncthreads();
    int node = blockIdx.x * 256 + threadIdx.x;
    if (node >= n) return;
    int beg = offsets[node], end = offsets[node + 1];
    float di = dinv[node];

    float acc[32];
    {
        const float4* p = reinterpret_cast<const float4*>(h2s + (long long)node * 32);
        set8(acc, p[0]); set8(acc + 8, p[1]); set8(acc + 16, p[2]); set8(acc + 24, p[3]);
    }
    for (int e = beg; e < end; ++e) {
        int s = sorted_src[e];
        const float4* p = reinterpret_cast<const float4*>(h2s + (long long)s * 32);
        acc8(acc, p[0]); acc8(acc + 8, p[1]); acc8(acc + 16, p[2]); acc8(acc + 24, p[3]);
    }

    float out[16];
#pragma unroll
    for (int f = 0; f < 16; ++f) out[f] = 0.0f;
#pragma unroll
    for (int k = 0; k < 32; ++k) {
        float v = fmaxf(fmaf(acc[k], di, sB2[k]), 0.0f);   // relu(acc*di + b2)
#pragma unroll
        for (int f = 0; f < 16; ++f) out[f] = fmaf(v, sW3[k * 16 + f], out[f]);
    }
#pragma unroll
    for (int f = 0; f < 16; ++f) out[f] *= di;

    float4* o = reinterpret_cast<float4*>(h3s + (long long)node * 16);
    o[0] = pack8(out);
    o[1] = pack8(out + 8);
}

// ---------------- fused layer 4: gather(16) -> +b3 relu -> 16->2 *di ---------
__global__ __launch_bounds__(256) void layer4_kernel(
    const __half* __restrict__ h3s, const float* __restrict__ dinv,
    const int* __restrict__ sorted_src, const int* __restrict__ offsets,
    const float* __restrict__ b3, const float* __restrict__ W4,
    __half* __restrict__ h4s, int n) {
    __shared__ float sW4[32];
    __shared__ float sB3[16];
    for (int i = threadIdx.x; i < 32; i += 256) sW4[i] = W4[i];
    for (int i = threadIdx.x; i < 16; i += 256) sB3[i] = b3[i];
    __syncthreads();
    int node = blockIdx.x * 256 + threadIdx.x;
    if (node >= n) return;
    int beg = offsets[node], end = offsets[node + 1];
    float di = dinv[node];

    float acc[16];
    {
        const float4* p = reinterpret_cast<const float4*>(h3s + (long long)node * 16);
        set8(acc, p[0]); set8(acc + 8, p[1]);
    }
    for (int e = beg; e < end; ++e) {
        int s = sorted_src[e];
        const float4* p = reinterpret_cast<const float4*>(h3s + (long long)s * 16);
        acc8(acc, p[0]); acc8(acc + 8, p[1]);
    }

    float o0 = 0.0f, o1 = 0.0f;
#pragma unroll
    for (int k = 0; k < 16; ++k) {
        float v = fmaxf(fmaf(acc[k], di, sB3[k]), 0.0f);
        o0 = fmaf(v, sW4[2 * k], o0);
        o1 = fmaf(v, sW4[2 * k + 1], o1);
    }
    *reinterpret_cast<__half2*>(h4s + 2LL * node) = __floats2half2_rn(o0 * di, o1 * di);
}

// ---------------- final: F=2 aggregation fused with log_softmax --------------
__global__ __launch_bounds__(256) void agg2_lsm_kernel(
    const __half* __restrict__ hs, const float* __restrict__ dinv,
    const int* __restrict__ sorted_src, const int* __restrict__ offsets,
    const float* __restrict__ b, float* __restrict__ out, int n) {
    int i = blockIdx.x * 256 + threadIdx.x;
    if (i >= n) return;
    int beg = offsets[i];
    int end = offsets[i + 1];
    float di = dinv[i];
    float2 acc = __half22float2(*reinterpret_cast<const __half2*>(hs + 2LL * i));
    for (int e = beg; e < end; ++e) {
        int s = sorted_src[e];
        float2 r = __half22float2(*reinterpret_cast<const __half2*>(hs + 2LL * s));
        acc.x += r.x; acc.y += r.y;
    }
    float a = acc.x * di + b[0];
    float c = acc.y * di + b[1];
    float m = fmaxf(a, c);
    float lse = m + logf(expf(a - m) + expf(c - m));
    out[2 * i]     = a - lse;
    out[2 * i + 1] = c - lse;
}

static inline int cdiv_ll(long long a, int b) { return (int)((a + b - 1) / b); }
static inline char* align16(char* p) { return (char*)(((uintptr_t)p + 15) & ~(uintptr_t)15); }

extern "C" void kernel_launch(void* const* d_in, const int* in_sizes, int n_in,
                              void* d_out, int out_size, void* d_ws, size_t ws_size,
                              hipStream_t stream) {
    (void)n_in; (void)out_size; (void)ws_size;

    const float* x  = (const float*)d_in[0];      // [N,18]
    const int*   ei = (const int*)d_in[1];        // [2,E]
    const float* W1 = (const float*)d_in[2];
    const float* b1 = (const float*)d_in[3];
    const float* W2 = (const float*)d_in[4];
    const float* b2 = (const float*)d_in[5];
    const float* W3 = (const float*)d_in[6];
    const float* b3 = (const float*)d_in[7];
    const float* W4 = (const float*)d_in[8];
    const float* b4 = (const float*)d_in[9];

    const int n = in_sizes[0] / 18;               // 100000
    const int E = in_sizes[1] / 2;                // 1600000
    const int* src = ei;
    const int* dst = ei + E;
    const int nbuck = (n + 255) >> NBUCK_SHIFT;   // 391

    // ---- workspace layout (16B-aligned regions, no aliasing) ----
    char* p = (char*)d_ws;
    int*    hist       = (int*)p;            p = align16(p + 512 * 4);
    int*    bbase      = (int*)p;            p = align16(p + 512 * 4);
    int*    gcur       = (int*)p;            p = align16(p + 512 * 4);
    int*    offsets    = (int*)p;            p = align16(p + (size_t)(n + 1) * 4);
    float*  dinv       = (float*)p;          p = align16(p + (size_t)n * 4);
    int*    sorted_src = (int*)p;            p = align16(p + (size_t)E * 4);
    unsigned int* bucketed = (unsigned int*)p; p = align16(p + (size_t)E * 4);
    __half* xs         = (__half*)p;         p = align16(p + (size_t)n * 24 * 2);  // 4.8MB
    __half* h2s        = (__half*)p;         p = align16(p + (size_t)n * 32 * 2);  // 6.4MB
    __half* h3s        = (__half*)p;         p = align16(p + (size_t)n * 16 * 2);  // 3.2MB
    __half* h4s        = (__half*)p;         p = align16(p + (size_t)n * 2 * 2);   // 0.4MB

    const int B = 256;
    const int NODE_BLOCKS = cdiv_ll(n, B);

    // ---- CSR-by-dst via bucketed counting sort ----
    hipMemsetAsync(hist, 0, 512 * 4, stream);
    hist_kernel<<<512, B, 0, stream>>>(dst, hist, E, nbuck);
    scan_hist_kernel<<<1, 512, 0, stream>>>(hist, bbase, gcur, nbuck, E);
    partition_kernel<<<cdiv_ll(E, PART_CHUNK), B, 0, stream>>>(src, dst, gcur, bucketed, E, nbuck);
    csr_kernel<<<nbuck, B, 0, stream>>>(bucketed, bbase, offsets, dinv, sorted_src, n, E);

    // ---- fused pipeline ----
    scale_pad18_kernel<<<NODE_BLOCKS, B, 0, stream>>>(x, dinv, xs, n);
    layer12_kernel<<<NODE_BLOCKS, B, 0, stream>>>(xs, dinv, sorted_src, offsets, W1, b1, W2, h2s, n);
    layer3_kernel<<<NODE_BLOCKS, B, 0, stream>>>(h2s, dinv, sorted_src, offsets, b2, W3, h3s, n);
    layer4_kernel<<<NODE_BLOCKS, B, 0, stream>>>(h3s, dinv, sorted_src, offsets, b3, W4, h4s, n);
    agg2_lsm_kernel<<<NODE_BLOCKS, B, 0, stream>>>(h4s, dinv, sorted_src, offsets, b4, (float*)d_out, n);
}

// Round 6
// 246.203 us; speedup vs baseline: 7.0239x; 1.0834x over previous
//
#include <hip/hip_runtime.h>
#include <hip/hip_bf16.h>
#include <hip/hip_fp16.h>

// ============================================================================
// GCN forward. CSR-by-dst via two-level bucketed counting sort; fused
// "gather + dense" layer kernels with 4 lanes per node (edge-split) for
// occupancy: each lane aggregates 1/4 of the node's edges in registers,
// lanes combine via __shfl_xor butterflies / reduce-scatters, dense layers
// applied split across the 4 lanes with LDS-resident (bank-padded) weights.
//
// Algebra: A_hat(xW) = (A_hat x)W, normalization factored as
//   out[d] = dinv[d] * ( sum_{s in N(d)} hs[s] + hs[d] ) + b,  hs = h*dinv[row]
// with hs stored fp16 (fp32 accumulation). Tables: xs=4.8MB, h2s=6.4MB,
// h3s=3.2MB, h4s=0.4MB -> L2/L3 resident gathers.
// ============================================================================

#define NBUCK_SHIFT 8            // 256 nodes per bucket
#define PART_CHUNK  4096         // edges per partition block (256 thr x 16)

// ---------------- pass A: bucket histogram ----------------
__global__ __launch_bounds__(256) void hist_kernel(const int* __restrict__ dst,
                                                   int* __restrict__ hist,
                                                   int n_edges, int nbuck) {
    __shared__ int h[512];
    for (int i = threadIdx.x; i < 512; i += 256) h[i] = 0;
    __syncthreads();
    for (long long e = (long long)blockIdx.x * 256 + threadIdx.x; e < n_edges;
         e += (long long)gridDim.x * 256)
        atomicAdd(&h[dst[e] >> NBUCK_SHIFT], 1);
    __syncthreads();
    for (int i = threadIdx.x; i < nbuck; i += 256)
        if (h[i]) atomicAdd(&hist[i], h[i]);
}

// ---------------- pass A': scan bucket sizes (single block) ----------------
__global__ void scan_hist_kernel(const int* __restrict__ hist, int* __restrict__ base,
                                 int* __restrict__ gcur, int nbuck, int total) {
    __shared__ int s[512];
    int v = (threadIdx.x < nbuck) ? hist[threadIdx.x] : 0;
    s[threadIdx.x] = v;
    __syncthreads();
    for (int off = 1; off < 512; off <<= 1) {
        int t = (threadIdx.x >= off) ? s[threadIdx.x - off] : 0;
        __syncthreads();
        s[threadIdx.x] += t;
        __syncthreads();
    }
    if (threadIdx.x < nbuck) {
        int b = s[threadIdx.x] - v;   // exclusive
        base[threadIdx.x] = b;
        gcur[threadIdx.x] = b;
    }
    if (threadIdx.x == 0) base[nbuck] = total;
}

// ---------------- pass B: partition edges into buckets ----------------
// staged word: (src << 8) | (dst & 255)
__global__ __launch_bounds__(256) void partition_kernel(const int* __restrict__ src,
                                                        const int* __restrict__ dst,
                                                        int* __restrict__ gcur,
                                                        unsigned int* __restrict__ bucketed,
                                                        int n_edges, int nbuck) {
    __shared__ int cnt[512];
    __shared__ int base[512];
    const int t = threadIdx.x;
    for (int i = t; i < 512; i += 256) cnt[i] = 0;
    __syncthreads();
    long long start = (long long)blockIdx.x * PART_CHUNK;
    int sv[16], dv[16], bv[16];
#pragma unroll
    for (int k = 0; k < 16; ++k) {
        long long e = start + (long long)k * 256 + t;
        bool ok = e < n_edges;
        sv[k] = ok ? src[e] : 0;
        dv[k] = ok ? dst[e] : 0;
        bv[k] = ok ? (dv[k] >> NBUCK_SHIFT) : -1;
        if (ok) atomicAdd(&cnt[bv[k]], 1);
    }
    __syncthreads();
    for (int i = t; i < nbuck; i += 256) {
        int c = cnt[i];
        base[i] = c ? atomicAdd(&gcur[i], c) : 0;
    }
    __syncthreads();
    for (int i = t; i < 512; i += 256) cnt[i] = 0;   // reuse as running cursor
    __syncthreads();
#pragma unroll
    for (int k = 0; k < 16; ++k) {
        if (bv[k] >= 0) {
            int pos = base[bv[k]] + atomicAdd(&cnt[bv[k]], 1);
            bucketed[pos] = ((unsigned int)sv[k] << 8) | (unsigned int)(dv[k] & 255);
        }
    }
}

// ---------------- pass C: per-bucket CSR finalize ----------------
__global__ __launch_bounds__(256) void csr_kernel(const unsigned int* __restrict__ bucketed,
                                                  const int* __restrict__ base,
                                                  int* __restrict__ offsets,
                                                  float* __restrict__ dinv,
                                                  int* __restrict__ sorted_src,
                                                  int n, int n_edges) {
    __shared__ int ldeg[256];
    __shared__ int lscan[256];
    const int b = blockIdx.x;
    const int t = threadIdx.x;
    const int beg = base[b], end = base[b + 1];
    ldeg[t] = 0;
    __syncthreads();
    for (int e = beg + t; e < end; e += 256) {
        unsigned int p = bucketed[e];
        atomicAdd(&ldeg[p & 255u], 1);
    }
    __syncthreads();
    int v = ldeg[t];
    lscan[t] = v;
    __syncthreads();
    for (int off = 1; off < 256; off <<= 1) {
        int x = (t >= off) ? lscan[t - off] : 0;
        __syncthreads();
        lscan[t] += x;
        __syncthreads();
    }
    int excl = lscan[t] - v;                         // exclusive scan
    int node = (b << NBUCK_SHIFT) + t;
    if (node < n) {
        offsets[node] = beg + excl;
        dinv[node]    = rsqrtf((float)v + 1.0f);     // +1 self-loop
    }
    if (b == 0 && t == 0) offsets[n] = n_edges;
    __syncthreads();
    lscan[t] = beg + excl;                           // reuse as placement cursor
    __syncthreads();
    for (int e = beg + t; e < end; e += 256) {
        unsigned int p = bucketed[e];
        int pos = atomicAdd(&lscan[p & 255u], 1);
        sorted_src[pos] = (int)(p >> 8);
    }
}

// ---------------- helpers ----------------
__device__ inline void acc8(float* acc, float4 raw) {
    const __half2* h2 = reinterpret_cast<const __half2*>(&raw);
#pragma unroll
    for (int j = 0; j < 4; ++j) {
        float2 v = __half22float2(h2[j]);
        acc[2 * j]     += v.x;
        acc[2 * j + 1] += v.y;
    }
}
__device__ inline float4 pack8(const float* v) {
    float4 out;
    __half2* h2 = reinterpret_cast<__half2*>(&out);
#pragma unroll
    for (int j = 0; j < 4; ++j) h2[j] = __floats2half2_rn(v[2 * j], v[2 * j + 1]);
    return out;
}

// ---------------- xs[node, 0..23] = half(x[node,0..17] * dinv[node]), padded --
__global__ __launch_bounds__(256) void scale_pad18_kernel(const float* __restrict__ x,
                                                          const float* __restrict__ dinv,
                                                          __half* __restrict__ xs, int n) {
    int node = blockIdx.x * 256 + threadIdx.x;
    if (node >= n) return;
    float di = dinv[node];
    const float* xr = x + (long long)node * 18;
    float v[24];
#pragma unroll
    for (int k = 0; k < 18; ++k) v[k] = xr[k] * di;
#pragma unroll
    for (int k = 18; k < 24; ++k) v[k] = 0.0f;
    float4* o = reinterpret_cast<float4*>(xs + (long long)node * 24);
    o[0] = pack8(v);
    o[1] = pack8(v + 8);
    o[2] = pack8(v + 16);
}

// ---------------- fused layer 1+2 (4 lanes/node) ----------------------------
// gather(18, edge-split) -> allreduce -> 18->64 relu (16 j's/lane)
// -> 64->32 partials -> reduce-scatter -> each lane stores 8 fp16.
__global__ __launch_bounds__(256) void layer12_kernel(
    const __half* __restrict__ xs, const float* __restrict__ dinv,
    const int* __restrict__ sorted_src, const int* __restrict__ offsets,
    const float* __restrict__ W1, const float* __restrict__ b1,
    const float* __restrict__ W2, __half* __restrict__ h2s, int n) {
    __shared__ float sW1[18 * 65];   // +1 pad: lane j-stride 16 -> 2-way (free)
    __shared__ float sB1[64];
    __shared__ float sW2[64 * 33];   // +1 pad
    for (int i = threadIdx.x; i < 18 * 64; i += 256) sW1[(i / 64) * 65 + (i % 64)] = W1[i];
    for (int i = threadIdx.x; i < 64; i += 256) sB1[i] = b1[i];
    for (int i = threadIdx.x; i < 64 * 32; i += 256) sW2[(i / 32) * 33 + (i % 32)] = W2[i];
    __syncthreads();

    long long gt = (long long)blockIdx.x * 256 + threadIdx.x;
    int node = (int)(gt >> 2);
    int l4   = (int)(gt & 3);
    if (node >= n) return;
    int beg = offsets[node], end = offsets[node + 1];
    float di = dinv[node];

    float acc[24];
#pragma unroll
    for (int j = 0; j < 24; ++j) acc[j] = 0.0f;
    if (l4 == 3) {   // lane 3 has the fewest edges; give it the self row
        const float4* pp = reinterpret_cast<const float4*>(xs + (long long)node * 24);
        acc8(acc, pp[0]); acc8(acc + 8, pp[1]); acc8(acc + 16, pp[2]);
    }
    for (int e = beg + l4; e < end; e += 4) {
        int s = sorted_src[e];
        const float4* pp = reinterpret_cast<const float4*>(xs + (long long)s * 24);
        acc8(acc, pp[0]); acc8(acc + 8, pp[1]); acc8(acc + 16, pp[2]);
    }
    // all-reduce acc across the 4-lane group (every lane needs all 18 dims)
#pragma unroll
    for (int j = 0; j < 24; ++j) {
        acc[j] += __shfl_xor(acc[j], 1);
        acc[j] += __shfl_xor(acc[j], 2);
    }

    // hidden slice: lane computes j in [16*l4, 16*l4+16)
    const int j0 = l4 * 16;
    float hidden[16];
#pragma unroll
    for (int jj = 0; jj < 16; ++jj) hidden[jj] = sB1[j0 + jj];
#pragma unroll
    for (int k = 0; k < 18; ++k) {
        float a = acc[k] * di;
#pragma unroll
        for (int jj = 0; jj < 16; ++jj)
            hidden[jj] = fmaf(a, sW1[k * 65 + j0 + jj], hidden[jj]);
    }
#pragma unroll
    for (int jj = 0; jj < 16; ++jj) hidden[jj] = fmaxf(hidden[jj], 0.0f);

    // out partials over this lane's 16 hidden values
    float out[32];
#pragma unroll
    for (int f = 0; f < 32; ++f) out[f] = 0.0f;
#pragma unroll
    for (int jj = 0; jj < 16; ++jj) {
        float a = hidden[jj];
#pragma unroll
        for (int f = 0; f < 32; ++f)
            out[f] = fmaf(a, sW2[(j0 + jj) * 33 + f], out[f]);
    }
    // reduce-scatter out[32] -> lane l4 owns [8*l4, 8*l4+8)
    const bool hi2 = (l4 & 2);
    float h16[16];
#pragma unroll
    for (int v = 0; v < 16; ++v) {
        float keep = hi2 ? out[16 + v] : out[v];
        float send = hi2 ? out[v] : out[16 + v];
        h16[v] = keep + __shfl_xor(send, 2);
    }
    const bool hi1 = (l4 & 1);
    float q8[8];
#pragma unroll
    for (int v = 0; v < 8; ++v) {
        float keep = hi1 ? h16[8 + v] : h16[v];
        float send = hi1 ? h16[v] : h16[8 + v];
        q8[v] = (keep + __shfl_xor(send, 1)) * di;
    }
    *reinterpret_cast<float4*>(h2s + (long long)node * 32 + l4 * 8) = pack8(q8);
}

// ---------------- fused layer 3 (4 lanes/node) ------------------------------
// gather(32, edge-split) -> reduce-scatter (lane owns 8 k's) -> relu(+b2)
// -> 32->16 partials -> reduce-scatter -> lane stores 4 fp16.
__global__ __launch_bounds__(256) void layer3_kernel(
    const __half* __restrict__ h2s, const float* __restrict__ dinv,
    const int* __restrict__ sorted_src, const int* __restrict__ offsets,
    const float* __restrict__ b2, const float* __restrict__ W3,
    __half* __restrict__ h3s, int n) {
    __shared__ float sW3[32 * 17];   // +1 pad: lane k-stride 8 -> distinct banks
    __shared__ float sB2[32];
    for (int i = threadIdx.x; i < 32 * 16; i += 256) sW3[(i / 16) * 17 + (i % 16)] = W3[i];
    for (int i = threadIdx.x; i < 32; i += 256) sB2[i] = b2[i];
    __syncthreads();

    long long gt = (long long)blockIdx.x * 256 + threadIdx.x;
    int node = (int)(gt >> 2);
    int l4   = (int)(gt & 3);
    if (node >= n) return;
    int beg = offsets[node], end = offsets[node + 1];
    float di = dinv[node];

    float acc[32];
#pragma unroll
    for (int j = 0; j < 32; ++j) acc[j] = 0.0f;
    if (l4 == 3) {
        const float4* pp = reinterpret_cast<const float4*>(h2s + (long long)node * 32);
        acc8(acc, pp[0]); acc8(acc + 8, pp[1]); acc8(acc + 16, pp[2]); acc8(acc + 24, pp[3]);
    }
    for (int e = beg + l4; e < end; e += 4) {
        int s = sorted_src[e];
        const float4* pp = reinterpret_cast<const float4*>(h2s + (long long)s * 32);
        acc8(acc, pp[0]); acc8(acc + 8, pp[1]); acc8(acc + 16, pp[2]); acc8(acc + 24, pp[3]);
    }
    // reduce-scatter acc[32] -> lane owns k in [8*l4, 8*l4+8)
    const bool hi2 = (l4 & 2);
    float h16[16];
#pragma unroll
    for (int v = 0; v < 16; ++v) {
        float keep = hi2 ? acc[16 + v] : acc[v];
        float send = hi2 ? acc[v] : acc[16 + v];
        h16[v] = keep + __shfl_xor(send, 2);
    }
    const bool hi1 = (l4 & 1);
    float k8[8];
#pragma unroll
    for (int v = 0; v < 8; ++v) {
        float keep = hi1 ? h16[8 + v] : h16[v];
        float send = hi1 ? h16[v] : h16[8 + v];
        k8[v] = keep + __shfl_xor(send, 1);
    }

    // dense partials from this lane's 8 k's
    const int k0 = l4 * 8;
    float out[16];
#pragma unroll
    for (int f = 0; f < 16; ++f) out[f] = 0.0f;
#pragma unroll
    for (int kk = 0; kk < 8; ++kk) {
        float v = fmaxf(fmaf(k8[kk], di, sB2[k0 + kk]), 0.0f);
#pragma unroll
        for (int f = 0; f < 16; ++f)
            out[f] = fmaf(v, sW3[(k0 + kk) * 17 + f], out[f]);
    }
    // reduce-scatter out[16] -> lane owns [4*l4, 4*l4+4)
    float o8[8];
#pragma unroll
    for (int v = 0; v < 8; ++v) {
        float keep = hi2 ? out[8 + v] : out[v];
        float send = hi2 ? out[v] : out[8 + v];
        o8[v] = keep + __shfl_xor(send, 2);
    }
    float o4[4];
#pragma unroll
    for (int v = 0; v < 4; ++v) {
        float keep = hi1 ? o8[4 + v] : o8[v];
        float send = hi1 ? o8[v] : o8[4 + v];
        o4[v] = (keep + __shfl_xor(send, 1)) * di;
    }
    union { float2 f2; __half2 h2[2]; } u;
    u.h2[0] = __floats2half2_rn(o4[0], o4[1]);
    u.h2[1] = __floats2half2_rn(o4[2], o4[3]);
    *reinterpret_cast<float2*>(h3s + (long long)node * 16 + l4 * 4) = u.f2;
}

// ---------------- fused layer 4 (4 lanes/node) ------------------------------
// gather(16, edge-split) -> reduce-scatter (lane owns 4 k's) -> relu(+b3)
// -> 16->2 partials -> all-reduce -> lane0 stores fp16x2.
__global__ __launch_bounds__(256) void layer4_kernel(
    const __half* __restrict__ h3s, const float* __restrict__ dinv,
    const int* __restrict__ sorted_src, const int* __restrict__ offsets,
    const float* __restrict__ b3, const float* __restrict__ W4,
    __half* __restrict__ h4s, int n) {
    __shared__ float sW4[32];
    __shared__ float sB3[16];
    for (int i = threadIdx.x; i < 32; i += 256) sW4[i] = W4[i];
    for (int i = threadIdx.x; i < 16; i += 256) sB3[i] = b3[i];
    __syncthreads();

    long long gt = (long long)blockIdx.x * 256 + threadIdx.x;
    int node = (int)(gt >> 2);
    int l4   = (int)(gt & 3);
    if (node >= n) return;
    int beg = offsets[node], end = offsets[node + 1];
    float di = dinv[node];

    float acc[16];
#pragma unroll
    for (int j = 0; j < 16; ++j) acc[j] = 0.0f;
    if (l4 == 3) {
        const float4* pp = reinterpret_cast<const float4*>(h3s + (long long)node * 16);
        acc8(acc, pp[0]); acc8(acc + 8, pp[1]);
    }
    for (int e = beg + l4; e < end; e += 4) {
        int s = sorted_src[e];
        const float4* pp = reinterpret_cast<const float4*>(h3s + (long long)s * 16);
        acc8(acc, pp[0]); acc8(acc + 8, pp[1]);
    }
    // reduce-scatter acc[16] -> lane owns k in [4*l4, 4*l4+4)
    const bool hi2 = (l4 & 2);
    float h8[8];
#pragma unroll
    for (int v = 0; v < 8; ++v) {
        float keep = hi2 ? acc[8 + v] : acc[v];
        float send = hi2 ? acc[v] : acc[8 + v];
        h8[v] = keep + __shfl_xor(send, 2);
    }
    const bool hi1 = (l4 & 1);
    float k4[4];
#pragma unroll
    for (int v = 0; v < 4; ++v) {
        float keep = hi1 ? h8[4 + v] : h8[v];
        float send = hi1 ? h8[v] : h8[4 + v];
        k4[v] = keep + __shfl_xor(send, 1);
    }
    const int k0 = l4 * 4;
    float o0 = 0.0f, o1 = 0.0f;
#pragma unroll
    for (int kk = 0; kk < 4; ++kk) {
        float v = fmaxf(fmaf(k4[kk], di, sB3[k0 + kk]), 0.0f);
        o0 = fmaf(v, sW4[2 * (k0 + kk)], o0);
        o1 = fmaf(v, sW4[2 * (k0 + kk) + 1], o1);
    }
    o0 += __shfl_xor(o0, 1); o0 += __shfl_xor(o0, 2);
    o1 += __shfl_xor(o1, 1); o1 += __shfl_xor(o1, 2);
    if (l4 == 0)
        *reinterpret_cast<__half2*>(h4s + 2LL * node) = __floats2half2_rn(o0 * di, o1 * di);
}

// ---------------- final: F=2 aggregation + log_softmax (4 lanes/node) --------
__global__ __launch_bounds__(256) void agg2_lsm_kernel(
    const __half* __restrict__ hs, const float* __restrict__ dinv,
    const int* __restrict__ sorted_src, const int* __restrict__ offsets,
    const float* __restrict__ b, float* __restrict__ out, int n) {
    long long gt = (long long)blockIdx.x * 256 + threadIdx.x;
    int node = (int)(gt >> 2);
    int l4   = (int)(gt & 3);
    if (node >= n) return;
    int beg = offsets[node], end = offsets[node + 1];
    float ax = 0.0f, ay = 0.0f;
    if (l4 == 3) {
        float2 r = __half22float2(*reinterpret_cast<const __half2*>(hs + 2LL * node));
        ax += r.x; ay += r.y;
    }
    for (int e = beg + l4; e < end; e += 4) {
        int s = sorted_src[e];
        float2 r = __half22float2(*reinterpret_cast<const __half2*>(hs + 2LL * s));
        ax += r.x; ay += r.y;
    }
    ax += __shfl_xor(ax, 1); ax += __shfl_xor(ax, 2);
    ay += __shfl_xor(ay, 1); ay += __shfl_xor(ay, 2);
    if (l4 == 0) {
        float di = dinv[node];
        float a = ax * di + b[0];
        float c = ay * di + b[1];
        float m = fmaxf(a, c);
        float lse = m + logf(expf(a - m) + expf(c - m));
        float2 r = make_float2(a - lse, c - lse);
        *reinterpret_cast<float2*>(out + 2LL * node) = r;
    }
}

static inline int cdiv_ll(long long a, int b) { return (int)((a + b - 1) / b); }
static inline char* align16(char* p) { return (char*)(((uintptr_t)p + 15) & ~(uintptr_t)15); }

extern "C" void kernel_launch(void* const* d_in, const int* in_sizes, int n_in,
                              void* d_out, int out_size, void* d_ws, size_t ws_size,
                              hipStream_t stream) {
    (void)n_in; (void)out_size; (void)ws_size;

    const float* x  = (const float*)d_in[0];      // [N,18]
    const int*   ei = (const int*)d_in[1];        // [2,E]
    const float* W1 = (const float*)d_in[2];
    const float* b1 = (const float*)d_in[3];
    const float* W2 = (const float*)d_in[4];
    const float* b2 = (const float*)d_in[5];
    const float* W3 = (const float*)d_in[6];
    const float* b3 = (const float*)d_in[7];
    const float* W4 = (const float*)d_in[8];
    const float* b4 = (const float*)d_in[9];

    const int n = in_sizes[0] / 18;               // 100000
    const int E = in_sizes[1] / 2;                // 1600000
    const int* src = ei;
    const int* dst = ei + E;
    const int nbuck = (n + 255) >> NBUCK_SHIFT;   // 391

    // ---- workspace layout (16B-aligned regions, no aliasing) ----
    char* p = (char*)d_ws;
    int*    hist       = (int*)p;            p = align16(p + 512 * 4);
    int*    bbase      = (int*)p;            p = align16(p + 512 * 4);
    int*    gcur       = (int*)p;            p = align16(p + 512 * 4);
    int*    offsets    = (int*)p;            p = align16(p + (size_t)(n + 1) * 4);
    float*  dinv       = (float*)p;          p = align16(p + (size_t)n * 4);
    int*    sorted_src = (int*)p;            p = align16(p + (size_t)E * 4);
    unsigned int* bucketed = (unsigned int*)p; p = align16(p + (size_t)E * 4);
    __half* xs         = (__half*)p;         p = align16(p + (size_t)n * 24 * 2);  // 4.8MB
    __half* h2s        = (__half*)p;         p = align16(p + (size_t)n * 32 * 2);  // 6.4MB
    __half* h3s        = (__half*)p;         p = align16(p + (size_t)n * 16 * 2);  // 3.2MB
    __half* h4s        = (__half*)p;         p = align16(p + (size_t)n * 2 * 2);   // 0.4MB

    const int B = 256;
    const int NODE_BLOCKS  = cdiv_ll(n, B);
    const int NODE4_BLOCKS = cdiv_ll(4LL * n, B);

    // ---- CSR-by-dst via bucketed counting sort ----
    hipMemsetAsync(hist, 0, 512 * 4, stream);
    hist_kernel<<<512, B, 0, stream>>>(dst, hist, E, nbuck);
    scan_hist_kernel<<<1, 512, 0, stream>>>(hist, bbase, gcur, nbuck, E);
    partition_kernel<<<cdiv_ll(E, PART_CHUNK), B, 0, stream>>>(src, dst, gcur, bucketed, E, nbuck);
    csr_kernel<<<nbuck, B, 0, stream>>>(bucketed, bbase, offsets, dinv, sorted_src, n, E);

    // ---- fused pipeline (4 lanes/node) ----
    scale_pad18_kernel<<<NODE_BLOCKS, B, 0, stream>>>(x, dinv, xs, n);
    layer12_kernel<<<NODE4_BLOCKS, B, 0, stream>>>(xs, dinv, sorted_src, offsets, W1, b1, W2, h2s, n);
    layer3_kernel<<<NODE4_BLOCKS, B, 0, stream>>>(h2s, dinv, sorted_src, offsets, b2, W3, h3s, n);
    layer4_kernel<<<NODE4_BLOCKS, B, 0, stream>>>(h3s, dinv, sorted_src, offsets, b3, W4, h4s, n);
    agg2_lsm_kernel<<<NODE4_BLOCKS, B, 0, stream>>>(h4s, dinv, sorted_src, offsets, b4, (float*)d_out, n);
}